// Round 5
// baseline (8206.990 us; speedup 1.0000x reference)
//
#include <hip/hip_runtime.h>
#include <hip/hip_bf16.h>

#define B_ 64
#define T_ 256
#define EMB_ 512
#define HID_ 1024
#define G4_ 4096
#define NCLS_ 32000
#define BH (B_ * HID_)
#define WS1 1032  // LDS W_ih row stride (f16), layer1: 1024+8 pad
#define WS0 520   // layer0: 512+8

typedef _Float16 f16;
typedef _Float16 f16x8 __attribute__((ext_vector_type(8)));
typedef _Float16 f16x4 __attribute__((ext_vector_type(4)));
typedef _Float16 f16x2 __attribute__((ext_vector_type(2)));
typedef float f32x4 __attribute__((ext_vector_type(4)));
typedef unsigned long long u64;

__device__ __forceinline__ float sigm(float x) { return 1.f / (1.f + __expf(-x)); }

// LLC-coherent (cross-XCD) accessors: relaxed agent-scope atomics bypass the
// non-coherent per-XCD L2 (mechanism validated in R3: correct + fast).
__device__ __forceinline__ void stg_u32(unsigned* p, unsigned v) {
  __hip_atomic_store(p, v, __ATOMIC_RELAXED, __HIP_MEMORY_SCOPE_AGENT);
}
__device__ __forceinline__ u64 ldg_u64(const void* p) {
  return __hip_atomic_load((const u64*)p, __ATOMIC_RELAXED, __HIP_MEMORY_SCOPE_AGENT);
}

// ---------------- prep kernels ----------------

__global__ __launch_bounds__(256) void cvt_kernel(const float* __restrict__ src,
                                                  f16* __restrict__ dst, int n4) {
  int i = blockIdx.x * 256 + threadIdx.x;
  if (i < n4) {
    float4 v = ((const float4*)src)[i];
    f16x4 o = {(f16)v.x, (f16)v.y, (f16)v.z, (f16)v.w};
    *(f16x4*)(dst + (size_t)i * 4) = o;
  }
}

__global__ __launch_bounds__(256) void bsum_kernel(const float* __restrict__ a0,
                                                   const float* __restrict__ b0,
                                                   float* __restrict__ o0,
                                                   const float* __restrict__ a1,
                                                   const float* __restrict__ b1,
                                                   float* __restrict__ o1) {
  int i = blockIdx.x * 256 + threadIdx.x;
  if (i < G4_) {
    o0[i] = a0[i] + b0[i];
    o1[i] = a1[i] + b1[i];
  }
}

// x0 layout: [T][B][EMB] fp16
__global__ __launch_bounds__(128) void gather_kernel(const int* __restrict__ tokens,
                                                     const float* __restrict__ emb,
                                                     f16* __restrict__ x0) {
  int blk = blockIdx.x;  // t*64 + b
  int t = blk >> 6, b = blk & 63;
  int tok = tokens[b * T_ + t];
  float4 v = ((const float4*)(emb + (size_t)tok * EMB_))[threadIdx.x];
  f16x4 o = {(f16)v.x, (f16)v.y, (f16)v.z, (f16)v.w};
  *(f16x4*)(x0 + (size_t)blk * EMB_ + threadIdx.x * 4) = o;
}

// ---------------- fused persistent recurrence kernel ----------------
// gates[t] = W_hh*h[t-1] + W_ih*xin[t] + bias : ONE GEMM (no xg intermediate).
//   blocks 0..63   (layer0): xin = x0[t],  K_ih=512,  computes t = s
//   blocks 64..127 (layer1): xin = h0[t],  K_ih=1024, computes t = s-1
// Per block: 64 gate-rows (16 h-units x 4 gates). W_hh slice in 32 f16x8 regs
// (FULLY unrolled use - compile-time indices only), W_ih slice in LDS.
// h rings: depth-257 single-assignment (normal cached loads OK - R3-proven).
// Sync: R3's proven FULL barrier each step: drain -> flag -> scan-all -> sync.
__global__ __launch_bounds__(512, 2) void persist_kernel(
    const f16* __restrict__ x0, const f16* __restrict__ w0i,
    const f16* __restrict__ w0h, const f16* __restrict__ w1i,
    const f16* __restrict__ w1h, const float* __restrict__ b0s,
    const float* __restrict__ b1s, f16* __restrict__ h0r,
    f16* __restrict__ h1r, unsigned* flags) {
  __shared__ f16 Ws[64 * WS1];     // 132.1 KB W_ih slice
  __shared__ float pre[64 * 68];   // 17.4 KB preact exchange
  __shared__ float cst[64 * 16];   // 4 KB cell state

  const int layer = (blockIdx.x >> 6) & 1;  // 0..63 -> L0, 64..127 -> L1 (both spread over all XCDs)
  const int g = blockIdx.x & 63;
  const int tid = threadIdx.x;
  const int lane = tid & 63, wave = tid >> 6;
  const int wm = wave & 1, wn = wave >> 1;  // wm: batch half, wn: gate (0..3)
  const int lr = lane & 15, lk = lane >> 4;
  const int j0 = g * 16;

  const f16* whh = layer ? w1h : w0h;
  const f16* wih = layer ? w1i : w0i;
  const float* bs = layer ? b1s : b0s;
  f16* hown = layer ? h1r : h0r;

  // ---- one-time preload: W_hh slice -> 32 f16x8 regs (full unroll everywhere)
  f16x8 breg[32];
  {
    const f16* p = whh + (size_t)(wn * HID_ + j0 + lr) * HID_ + lk * 8;
#pragma unroll
    for (int it = 0; it < 32; ++it) breg[it] = *(const f16x8*)(p + it * 32);
  }
  // ---- W_ih slice -> LDS
  if (layer) {
    for (int i = tid; i < 64 * 128; i += 512) {
      int r = i >> 7, c8 = i & 127;
      int grow = (r >> 4) * HID_ + j0 + (r & 15);
      *(uint4*)(Ws + r * WS1 + c8 * 8) = *(const uint4*)(wih + (size_t)grow * HID_ + c8 * 8);
    }
  } else {
    for (int i = tid; i < 64 * 64; i += 512) {
      int r = i >> 6, c8 = i & 63;
      int grow = (r >> 4) * HID_ + j0 + (r & 15);
      *(uint4*)(Ws + r * WS0 + c8 * 8) = *(const uint4*)(wih + (size_t)grow * EMB_ + c8 * 8);
    }
  }
  float brg[4][2];
  {
    int u2 = tid & 7;
#pragma unroll
    for (int gg = 0; gg < 4; ++gg)
#pragma unroll
      for (int e = 0; e < 2; ++e) brg[gg][e] = bs[gg * HID_ + j0 + u2 * 2 + e];
  }
  for (int i = tid; i < 1024; i += 512) cst[i] = 0.f;
  __syncthreads();

  for (int s = 0; s <= T_; ++s) {
    const int t = layer ? s - 1 : s;
    const bool active = layer ? (s >= 1) : (s < T_);

    if (active) {
      // ---- fused GEMM: acc = W_hh*h[t-1] (reg B) + W_ih*xin[t] (LDS B)
      f32x4 acc[2] = {};
      {
        const f16* A1 = hown + (size_t)t * BH;  // h[t-1] lives in slot t
        const f16* a0p = A1 + (size_t)(wm * 32 + lr) * HID_ + lk * 8;
        const f16* a1p = a0p + (size_t)16 * HID_;
#pragma unroll
        for (int it = 0; it < 32; ++it) {
          f16x8 a0 = *(const f16x8*)(a0p + it * 32);
          f16x8 a1 = *(const f16x8*)(a1p + it * 32);
          acc[0] = __builtin_amdgcn_mfma_f32_16x16x32_f16(a0, breg[it], acc[0], 0, 0, 0);
          acc[1] = __builtin_amdgcn_mfma_f32_16x16x32_f16(a1, breg[it], acc[1], 0, 0, 0);
        }
        if (layer) {
          const f16* A2 = h0r + (size_t)(t + 1) * BH;  // h0[t] in slot t+1
          const f16* b0p = A2 + (size_t)(wm * 32 + lr) * HID_ + lk * 8;
          const f16* b1p = b0p + (size_t)16 * HID_;
          const f16* wrow = Ws + (wn * 16 + lr) * WS1 + lk * 8;
#pragma unroll
          for (int it = 0; it < 32; ++it) {
            f16x8 a0 = *(const f16x8*)(b0p + it * 32);
            f16x8 a1 = *(const f16x8*)(b1p + it * 32);
            f16x8 bv = *(const f16x8*)(wrow + it * 32);
            acc[0] = __builtin_amdgcn_mfma_f32_16x16x32_f16(a0, bv, acc[0], 0, 0, 0);
            acc[1] = __builtin_amdgcn_mfma_f32_16x16x32_f16(a1, bv, acc[1], 0, 0, 0);
          }
        } else {
          const f16* A2 = x0 + (size_t)t * (B_ * EMB_);
          const f16* b0p = A2 + (size_t)(wm * 32 + lr) * EMB_ + lk * 8;
          const f16* b1p = b0p + (size_t)16 * EMB_;
          const f16* wrow = Ws + (wn * 16 + lr) * WS0 + lk * 8;
#pragma unroll
          for (int it = 0; it < 16; ++it) {
            f16x8 a0 = *(const f16x8*)(b0p + it * 32);
            f16x8 a1 = *(const f16x8*)(b1p + it * 32);
            f16x8 bv = *(const f16x8*)(wrow + it * 32);
            acc[0] = __builtin_amdgcn_mfma_f32_16x16x32_f16(a0, bv, acc[0], 0, 0, 0);
            acc[1] = __builtin_amdgcn_mfma_f32_16x16x32_f16(a1, bv, acc[1], 0, 0, 0);
          }
        }
      }

      // ---- exchange preacts via LDS (rows: gate*16+unit, cols: batch)
#pragma unroll
      for (int mf = 0; mf < 2; ++mf)
        *(f32x4*)(pre + (wn * 16 + lr) * 68 + wm * 32 + mf * 16 + lk * 4) = acc[mf];
      __syncthreads();

      // ---- LSTM elementwise: thread (u2,b) handles 2 units x 1 batch
      {
        f16* hout = hown + (size_t)(t + 1) * BH;
        int u2 = tid & 7, b = tid >> 3;
        f16x2 hv;
#pragma unroll
        for (int e = 0; e < 2; ++e) {
          int r = u2 * 2 + e;
          float pi = pre[(0 * 16 + r) * 68 + b] + brg[0][e];
          float pf = pre[(1 * 16 + r) * 68 + b] + brg[1][e];
          float pg = pre[(2 * 16 + r) * 68 + b] + brg[2][e];
          float po = pre[(3 * 16 + r) * 68 + b] + brg[3][e];
          float ig = sigm(pi), fg = sigm(pf), gg = tanhf(pg), og = sigm(po);
          float cn = fg * cst[b * 16 + r] + ig * gg;
          cst[b * 16 + r] = cn;
          hv[e] = (f16)(og * tanhf(cn));
        }
        stg_u32((unsigned*)(hout + (size_t)b * HID_ + j0 + u2 * 2),
                __builtin_bit_cast(unsigned, hv));
      }
    }

    // ---- R3-proven full grid barrier: drain -> flag -> scan ALL -> sync
    if (s < T_) {
      asm volatile("s_waitcnt vmcnt(0)" ::: "memory");
      __syncthreads();
      if (tid == 0) stg_u32(&flags[blockIdx.x], (unsigned)(s + 1));
      if (wave == 0) {
        const unsigned tgt = (unsigned)(s + 1);
        const u64* fp = (const u64*)flags;  // 128 flags = 64 u64, one per lane
        int iters = 0;
        for (;;) {
          u64 v = ldg_u64(&fp[lane]);
          bool ok = ((unsigned)v >= tgt) && ((unsigned)(v >> 32) >= tgt);
          if (__all(ok)) break;
          if (++iters > 2000000) break;  // safety valve: degrade, don't hang
          __builtin_amdgcn_s_sleep(2);
        }
      }
      __syncthreads();
    }
  }
}

// ---------------- FC kernel: out = h1_last @ fc_w^T + fc_b ----------------
__global__ __launch_bounds__(256) void fc_kernel(const f16* __restrict__ A,
                                                 const float* __restrict__ fcw,
                                                 const float* __restrict__ fcb,
                                                 float* __restrict__ out) {
  const int n0 = blockIdx.x * 64;
  __shared__ char smem[18432];
  f16* As = (f16*)smem;
  f16* Bs = (f16*)(smem + 9216);
  const int tid = threadIdx.x;
  const int lane = tid & 63, wave = tid >> 6;
  const int wm = wave & 1, wn = wave >> 1;
  const int lr = lane & 15, lk = lane >> 4;
  f32x4 acc[2][2] = {};

  for (int kt = 0; kt < HID_ / 64; ++kt) {
    const int k0 = kt * 64;
    __syncthreads();
#pragma unroll
    for (int i = 0; i < 2; ++i) {
      int id = tid + 256 * i;
      int r = id >> 3, c8 = id & 7;
      uint4 av = *(const uint4*)(A + (size_t)r * HID_ + k0 + c8 * 8);
      *(uint4*)(As + r * 72 + c8 * 8) = av;
    }
#pragma unroll
    for (int i = 0; i < 4; ++i) {
      int id = tid + 256 * i;
      int r = id >> 4, c4 = id & 15;
      float4 v = *(const float4*)(fcw + (size_t)(n0 + r) * HID_ + k0 + c4 * 4);
      f16x4 o = {(f16)v.x, (f16)v.y, (f16)v.z, (f16)v.w};
      *(f16x4*)(Bs + r * 72 + c4 * 4) = o;
    }
    __syncthreads();
#pragma unroll
    for (int ks = 0; ks < 2; ++ks) {
      f16x8 a0 = *(const f16x8*)(As + (wm * 32 + lr) * 72 + ks * 32 + lk * 8);
      f16x8 a1 = *(const f16x8*)(As + (wm * 32 + 16 + lr) * 72 + ks * 32 + lk * 8);
      f16x8 b0 = *(const f16x8*)(Bs + (wn * 32 + lr) * 72 + ks * 32 + lk * 8);
      f16x8 b1 = *(const f16x8*)(Bs + (wn * 32 + 16 + lr) * 72 + ks * 32 + lk * 8);
      acc[0][0] = __builtin_amdgcn_mfma_f32_16x16x32_f16(a0, b0, acc[0][0], 0, 0, 0);
      acc[0][1] = __builtin_amdgcn_mfma_f32_16x16x32_f16(a0, b1, acc[0][1], 0, 0, 0);
      acc[1][0] = __builtin_amdgcn_mfma_f32_16x16x32_f16(a1, b0, acc[1][0], 0, 0, 0);
      acc[1][1] = __builtin_amdgcn_mfma_f32_16x16x32_f16(a1, b1, acc[1][1], 0, 0, 0);
    }
  }

#pragma unroll
  for (int mf = 0; mf < 2; ++mf)
#pragma unroll
    for (int nf = 0; nf < 2; ++nf) {
      int n = n0 + wn * 32 + nf * 16 + lr;
      float bias = fcb[n];
      int bbase = wm * 32 + mf * 16 + lk * 4;
#pragma unroll
      for (int rg = 0; rg < 4; ++rg)
        out[(size_t)(bbase + rg) * NCLS_ + n] = acc[mf][nf][rg] + bias;
    }
}

// ---------------- launch ----------------

extern "C" void kernel_launch(void* const* d_in, const int* in_sizes, int n_in,
                              void* d_out, int out_size, void* d_ws,
                              size_t ws_size, hipStream_t stream) {
  const int* tokens = (const int*)d_in[0];
  const float* emb = (const float*)d_in[1];
  const float* W_ih0 = (const float*)d_in[2];
  const float* W_hh0 = (const float*)d_in[3];
  const float* b_ih0 = (const float*)d_in[4];
  const float* b_hh0 = (const float*)d_in[5];
  const float* W_ih1 = (const float*)d_in[6];
  const float* W_hh1 = (const float*)d_in[7];
  const float* b_ih1 = (const float*)d_in[8];
  const float* b_hh1 = (const float*)d_in[9];
  const float* fc_w = (const float*)d_in[10];
  const float* fc_b = (const float*)d_in[11];
  float* out = (float*)d_out;

  char* ws = (char*)d_ws;
  size_t off = 0;
  auto carve = [&](size_t bytes) -> char* {
    char* p = ws + off;
    off += (bytes + 255) & ~(size_t)255;
    return p;
  };
  f16* w0i = (f16*)carve((size_t)G4_ * EMB_ * 2);
  f16* w0h = (f16*)carve((size_t)G4_ * HID_ * 2);
  f16* w1i = (f16*)carve((size_t)G4_ * HID_ * 2);
  f16* w1h = (f16*)carve((size_t)G4_ * HID_ * 2);
  f16* x0 = (f16*)carve((size_t)T_ * B_ * EMB_ * 2);
  float* b0s = (float*)carve(G4_ * 4);
  float* b1s = (float*)carve(G4_ * 4);
  f16* h0r = (f16*)carve(257ull * BH * 2);  // slot t+1 = h[t]; slot 0 = zeros
  f16* h1r = (f16*)carve(257ull * BH * 2);
  unsigned* flags = (unsigned*)carve(128 * 4);

  hipMemsetAsync(flags, 0, 128 * 4, stream);
  hipMemsetAsync(h0r, 0, (size_t)BH * 2, stream);
  hipMemsetAsync(h1r, 0, (size_t)BH * 2, stream);

  cvt_kernel<<<(G4_ * EMB_ / 4 + 255) / 256, 256, 0, stream>>>(W_ih0, w0i, G4_ * EMB_ / 4);
  cvt_kernel<<<(G4_ * HID_ / 4 + 255) / 256, 256, 0, stream>>>(W_hh0, w0h, G4_ * HID_ / 4);
  cvt_kernel<<<(G4_ * HID_ / 4 + 255) / 256, 256, 0, stream>>>(W_ih1, w1i, G4_ * HID_ / 4);
  cvt_kernel<<<(G4_ * HID_ / 4 + 255) / 256, 256, 0, stream>>>(W_hh1, w1h, G4_ * HID_ / 4);
  bsum_kernel<<<(G4_ + 255) / 256, 256, 0, stream>>>(b_ih0, b_hh0, b0s, b_ih1, b_hh1, b1s);
  gather_kernel<<<T_ * B_, 128, 0, stream>>>(tokens, emb, x0);

  persist_kernel<<<128, 512, 0, stream>>>(x0, w0i, w0h, w1i, w1h, b0s, b1s,
                                          h0r, h1r, flags);

  fc_kernel<<<NCLS_ / 64, 256, 0, stream>>>(h1r + 256ull * BH, fc_w, fc_b, out);
}

// Round 6
// 3518.690 us; speedup vs baseline: 2.3324x; 2.3324x over previous
//
#include <hip/hip_runtime.h>
#include <hip/hip_bf16.h>

#define B_ 64
#define T_ 256
#define EMB_ 512
#define HID_ 1024
#define G4_ 4096
#define NCLS_ 32000
#define BH (B_ * HID_)

typedef _Float16 f16;
typedef _Float16 f16x8 __attribute__((ext_vector_type(8)));
typedef _Float16 f16x4 __attribute__((ext_vector_type(4)));
typedef _Float16 f16x2 __attribute__((ext_vector_type(2)));
typedef float f32x4 __attribute__((ext_vector_type(4)));
typedef unsigned long long u64;

__device__ __forceinline__ float sigm(float x) { return 1.f / (1.f + __expf(-x)); }

// LLC-coherent (cross-XCD) accessors (R3-proven: relaxed agent-scope atomics).
__device__ __forceinline__ void stg_u32(unsigned* p, unsigned v) {
  __hip_atomic_store(p, v, __ATOMIC_RELAXED, __HIP_MEMORY_SCOPE_AGENT);
}
__device__ __forceinline__ u64 ldg_u64(const void* p) {
  return __hip_atomic_load((const u64*)p, __ATOMIC_RELAXED, __HIP_MEMORY_SCOPE_AGENT);
}

// ---------------- prep kernels ----------------

__global__ __launch_bounds__(256) void cvt_kernel(const float* __restrict__ src,
                                                  f16* __restrict__ dst, int n4) {
  int i = blockIdx.x * 256 + threadIdx.x;
  if (i < n4) {
    float4 v = ((const float4*)src)[i];
    f16x4 o = {(f16)v.x, (f16)v.y, (f16)v.z, (f16)v.w};
    *(f16x4*)(dst + (size_t)i * 4) = o;
  }
}

__global__ __launch_bounds__(256) void bsum_kernel(const float* __restrict__ a0,
                                                   const float* __restrict__ b0,
                                                   float* __restrict__ o0,
                                                   const float* __restrict__ a1,
                                                   const float* __restrict__ b1,
                                                   float* __restrict__ o1) {
  int i = blockIdx.x * 256 + threadIdx.x;
  if (i < G4_) {
    o0[i] = a0[i] + b0[i];
    o1[i] = a1[i] + b1[i];
  }
}

// x0 layout: [T][B][EMB] fp16
__global__ __launch_bounds__(128) void gather_kernel(const int* __restrict__ tokens,
                                                     const float* __restrict__ emb,
                                                     f16* __restrict__ x0) {
  int blk = blockIdx.x;  // t*64 + b
  int t = blk >> 6, b = blk & 63;
  int tok = tokens[b * T_ + t];
  float4 v = ((const float4*)(emb + (size_t)tok * EMB_))[threadIdx.x];
  f16x4 o = {(f16)v.x, (f16)v.y, (f16)v.z, (f16)v.w};
  *(f16x4*)(x0 + (size_t)blk * EMB_ + threadIdx.x * 4) = o;
}

// ---------------- fused persistent recurrence kernel ----------------
// gates[t] = Wcat * [h[t-1]; xin[t]] + bias, Wcat = [W_hh | W_ih] in LDS.
//   blocks 0..127   (layer0): xin = x0[t]  (Kcat=1536), t = s
//   blocks 128..255 (layer1): xin = h0[t]  (Kcat=2048), t = s-1
// Per block: 32 gate-rows (4 gates x 8 units, j0 = slice*8).
// 8 waves = mi[2 batch-halves] x kq[4 K-quarters]; partial accs reduced in LDS.
// h rings: depth-257 single-assignment (normal cached loads, R3/R5-proven).
// Sync: R3's proven full barrier: drain -> flag -> scan-all-256 -> sync.
__global__ __launch_bounds__(512, 2) void persist_kernel(
    const f16* __restrict__ x0, const f16* __restrict__ w0i,
    const f16* __restrict__ w0h, const f16* __restrict__ w1i,
    const f16* __restrict__ w1h, const float* __restrict__ b0s,
    const float* __restrict__ b1s, f16* __restrict__ h0r,
    f16* __restrict__ h1r, unsigned* flags) {
  __shared__ f16 Ws[32 * 2056];     // 131584 B: 32 rows x (Kcat + 8 pad)
  __shared__ float red[6 * 64 * 17];  // 26112 B: K-partials; reused as pre[32][68]
  __shared__ float cst[512];        // 2 KB cell state [b][u]

  const int layer = blockIdx.x >> 7;
  const int slice = blockIdx.x & 127;
  const int tid = threadIdx.x;
  const int lane = tid & 63, wave = tid >> 6;
  const int mi = wave >> 2, kq = wave & 3;
  const int lr = lane & 15, lk = lane >> 4;
  const int j0 = slice * 8;

  const f16* whh = layer ? w1h : w0h;
  const f16* wih = layer ? w1i : w0i;
  const float* bs = layer ? b1s : b0s;
  f16* hown = layer ? h1r : h0r;
  const int KI = layer ? HID_ : EMB_;
  const int nch = (HID_ + KI) >> 3;       // uint4 chunks per row: 256 / 192
  const int wstr = HID_ + KI + 8;         // 2056 / 1544 (dword-stride % 32 == 4 -> 2-way, free)
  const int nks = (HID_ + KI) >> 5;       // total k-steps: 64 / 48
  const int KQ = nks >> 2;                // per-wave k-steps: 16 / 12

  // ---- one-time: stage Wcat = [W_hh | W_ih] rows into LDS ----
  for (int r = wave * 4; r < wave * 4 + 4; ++r) {
    int grow = (r >> 3) * HID_ + j0 + (r & 7);  // gate*HID + unit
    for (int c = lane; c < nch; c += 64) {
      int kk = c * 8;
      const f16* src = (kk < HID_) ? (whh + (size_t)grow * HID_ + kk)
                                   : (wih + (size_t)grow * KI + (kk - HID_));
      *(uint4*)(Ws + r * wstr + kk) = *(const uint4*)src;
    }
  }
  float brg[4][2];
  {
    int u2 = tid & 3;
#pragma unroll
    for (int g = 0; g < 4; ++g)
#pragma unroll
      for (int e = 0; e < 2; ++e) brg[g][e] = bs[g * HID_ + j0 + u2 * 2 + e];
  }
  for (int i = tid; i < 512; i += 512) cst[i] = 0.f;
  __syncthreads();

  for (int s = 0; s <= T_; ++s) {
    const int t = layer ? s - 1 : s;
    const bool active = layer ? (s >= 1) : (s < T_);

    if (active) {
      f32x4 acc00 = {}, acc01 = {}, acc10 = {}, acc11 = {};
      {
        const int lo = kq * KQ, hi = lo + KQ;
        const int h_hi = hi < 32 ? hi : 32;
        const int x_lo = lo > 32 ? lo : 32;
        const f16* hb = hown + (size_t)t * BH;
        const f16* xb = layer ? (h0r + (size_t)(t + 1) * BH)
                              : (x0 + (size_t)t * (B_ * EMB_));
        const int xstr = layer ? HID_ : EMB_;
        const int r0 = mi * 32 + lr, r1 = r0 + 16;
        const f16* wr0 = Ws + lr * wstr + lk * 8;
        const f16* wr1 = wr0 + 16 * wstr;
#pragma unroll 4
        for (int gk = lo; gk < h_hi; ++gk) {
          f16x8 a0 = *(const f16x8*)(hb + (size_t)r0 * HID_ + gk * 32 + lk * 8);
          f16x8 a1 = *(const f16x8*)(hb + (size_t)r1 * HID_ + gk * 32 + lk * 8);
          f16x8 b0 = *(const f16x8*)(wr0 + gk * 32);
          f16x8 b1 = *(const f16x8*)(wr1 + gk * 32);
          acc00 = __builtin_amdgcn_mfma_f32_16x16x32_f16(a0, b0, acc00, 0, 0, 0);
          acc01 = __builtin_amdgcn_mfma_f32_16x16x32_f16(a0, b1, acc01, 0, 0, 0);
          acc10 = __builtin_amdgcn_mfma_f32_16x16x32_f16(a1, b0, acc10, 0, 0, 0);
          acc11 = __builtin_amdgcn_mfma_f32_16x16x32_f16(a1, b1, acc11, 0, 0, 0);
        }
#pragma unroll 4
        for (int gk = x_lo; gk < hi; ++gk) {
          f16x8 a0 = *(const f16x8*)(xb + (size_t)r0 * xstr + (gk - 32) * 32 + lk * 8);
          f16x8 a1 = *(const f16x8*)(xb + (size_t)r1 * xstr + (gk - 32) * 32 + lk * 8);
          f16x8 b0 = *(const f16x8*)(wr0 + gk * 32);
          f16x8 b1 = *(const f16x8*)(wr1 + gk * 32);
          acc00 = __builtin_amdgcn_mfma_f32_16x16x32_f16(a0, b0, acc00, 0, 0, 0);
          acc01 = __builtin_amdgcn_mfma_f32_16x16x32_f16(a0, b1, acc01, 0, 0, 0);
          acc10 = __builtin_amdgcn_mfma_f32_16x16x32_f16(a1, b0, acc10, 0, 0, 0);
          acc11 = __builtin_amdgcn_mfma_f32_16x16x32_f16(a1, b1, acc11, 0, 0, 0);
        }
      }

      // ---- K-reduce: kq 1..3 publish (17-f32 lane stride: conflict-free) ----
      if (kq) {
        float* rp = red + ((mi * 3 + kq - 1) * 64 + lane) * 17;
        *(f32x4*)(rp) = acc00;      *(f32x4*)(rp + 4) = acc01;
        *(f32x4*)(rp + 8) = acc10;  *(f32x4*)(rp + 12) = acc11;
      }
      __syncthreads();  // A: partials visible
      if (!kq) {
#pragma unroll
        for (int q = 0; q < 3; ++q) {
          const float* rp = red + ((mi * 3 + q) * 64 + lane) * 17;
          acc00 += *(const f32x4*)(rp);      acc01 += *(const f32x4*)(rp + 4);
          acc10 += *(const f32x4*)(rp + 8);  acc11 += *(const f32x4*)(rp + 12);
        }
      }
      __syncthreads();  // B: all red reads done before pre overwrites red
      if (!kq) {
        float* pre = red;  // union
        int col = mi * 32 + lk * 4;
        *(f32x4*)(pre + (0 + lr) * 68 + col) = acc00;        // mf0 nf0
        *(f32x4*)(pre + (16 + lr) * 68 + col) = acc01;       // mf0 nf1
        *(f32x4*)(pre + (0 + lr) * 68 + col + 16) = acc10;   // mf1 nf0
        *(f32x4*)(pre + (16 + lr) * 68 + col + 16) = acc11;  // mf1 nf1
      }
      __syncthreads();  // C: pre ready

      // ---- LSTM elementwise: 256 threads x (1 batch, 2 units) ----
      if (tid < 256) {
        const float* pre = red;
        f16* hout = hown + (size_t)(t + 1) * BH;
        int u2 = tid & 3, b = tid >> 2;
        f16x2 hv;
#pragma unroll
        for (int e = 0; e < 2; ++e) {
          int r = u2 * 2 + e;
          float pi = pre[(0 * 8 + r) * 68 + b] + brg[0][e];
          float pf = pre[(1 * 8 + r) * 68 + b] + brg[1][e];
          float pg = pre[(2 * 8 + r) * 68 + b] + brg[2][e];
          float po = pre[(3 * 8 + r) * 68 + b] + brg[3][e];
          float ig = sigm(pi), fg = sigm(pf), gg = tanhf(pg), og = sigm(po);
          float cn = fg * cst[b * 8 + r] + ig * gg;
          cst[b * 8 + r] = cn;
          hv[e] = (f16)(og * tanhf(cn));
        }
        stg_u32((unsigned*)(hout + (size_t)b * HID_ + j0 + u2 * 2),
                __builtin_bit_cast(unsigned, hv));
      }
    }

    // ---- full grid barrier (R3-proven): drain -> flag -> scan-all -> sync ----
    if (s < T_) {
      asm volatile("s_waitcnt vmcnt(0)" ::: "memory");
      __syncthreads();  // D
      if (tid == 0) stg_u32(&flags[blockIdx.x], (unsigned)(s + 1));
      if (wave == 0) {
        const unsigned tgt = (unsigned)(s + 1);
        const u64* fp = (const u64*)flags;  // 256 flags = 128 u64
        int iters = 0;
        for (;;) {
          u64 a = ldg_u64(&fp[lane]);
          u64 b = ldg_u64(&fp[64 + lane]);
          bool ok = ((unsigned)a >= tgt) && ((unsigned)(a >> 32) >= tgt) &&
                    ((unsigned)b >= tgt) && ((unsigned)(b >> 32) >= tgt);
          if (__all(ok)) break;
          if (++iters > 2000000) break;  // safety valve: degrade, don't hang
          __builtin_amdgcn_s_sleep(2);
        }
      }
      __syncthreads();  // E
    }
  }
}

// ---------------- FC kernel: out = h1_last @ fc_w^T + fc_b ----------------
__global__ __launch_bounds__(256) void fc_kernel(const f16* __restrict__ A,
                                                 const float* __restrict__ fcw,
                                                 const float* __restrict__ fcb,
                                                 float* __restrict__ out) {
  const int n0 = blockIdx.x * 64;
  __shared__ char smem[18432];
  f16* As = (f16*)smem;
  f16* Bs = (f16*)(smem + 9216);
  const int tid = threadIdx.x;
  const int lane = tid & 63, wave = tid >> 6;
  const int wm = wave & 1, wn = wave >> 1;
  const int lr = lane & 15, lk = lane >> 4;
  f32x4 acc[2][2] = {};

  for (int kt = 0; kt < HID_ / 64; ++kt) {
    const int k0 = kt * 64;
    __syncthreads();
#pragma unroll
    for (int i = 0; i < 2; ++i) {
      int id = tid + 256 * i;
      int r = id >> 3, c8 = id & 7;
      uint4 av = *(const uint4*)(A + (size_t)r * HID_ + k0 + c8 * 8);
      *(uint4*)(As + r * 72 + c8 * 8) = av;
    }
#pragma unroll
    for (int i = 0; i < 4; ++i) {
      int id = tid + 256 * i;
      int r = id >> 4, c4 = id & 15;
      float4 v = *(const float4*)(fcw + (size_t)(n0 + r) * HID_ + k0 + c4 * 4);
      f16x4 o = {(f16)v.x, (f16)v.y, (f16)v.z, (f16)v.w};
      *(f16x4*)(Bs + r * 72 + c4 * 4) = o;
    }
    __syncthreads();
#pragma unroll
    for (int ks = 0; ks < 2; ++ks) {
      f16x8 a0 = *(const f16x8*)(As + (wm * 32 + lr) * 72 + ks * 32 + lk * 8);
      f16x8 a1 = *(const f16x8*)(As + (wm * 32 + 16 + lr) * 72 + ks * 32 + lk * 8);
      f16x8 b0 = *(const f16x8*)(Bs + (wn * 32 + lr) * 72 + ks * 32 + lk * 8);
      f16x8 b1 = *(const f16x8*)(Bs + (wn * 32 + 16 + lr) * 72 + ks * 32 + lk * 8);
      acc[0][0] = __builtin_amdgcn_mfma_f32_16x16x32_f16(a0, b0, acc[0][0], 0, 0, 0);
      acc[0][1] = __builtin_amdgcn_mfma_f32_16x16x32_f16(a0, b1, acc[0][1], 0, 0, 0);
      acc[1][0] = __builtin_amdgcn_mfma_f32_16x16x32_f16(a1, b0, acc[1][0], 0, 0, 0);
      acc[1][1] = __builtin_amdgcn_mfma_f32_16x16x32_f16(a1, b1, acc[1][1], 0, 0, 0);
    }
  }

#pragma unroll
  for (int mf = 0; mf < 2; ++mf)
#pragma unroll
    for (int nf = 0; nf < 2; ++nf) {
      int n = n0 + wn * 32 + nf * 16 + lr;
      float bias = fcb[n];
      int bbase = wm * 32 + mf * 16 + lk * 4;
#pragma unroll
      for (int rg = 0; rg < 4; ++rg)
        out[(size_t)(bbase + rg) * NCLS_ + n] = acc[mf][nf][rg] + bias;
    }
}

// ---------------- launch ----------------

extern "C" void kernel_launch(void* const* d_in, const int* in_sizes, int n_in,
                              void* d_out, int out_size, void* d_ws,
                              size_t ws_size, hipStream_t stream) {
  const int* tokens = (const int*)d_in[0];
  const float* emb = (const float*)d_in[1];
  const float* W_ih0 = (const float*)d_in[2];
  const float* W_hh0 = (const float*)d_in[3];
  const float* b_ih0 = (const float*)d_in[4];
  const float* b_hh0 = (const float*)d_in[5];
  const float* W_ih1 = (const float*)d_in[6];
  const float* W_hh1 = (const float*)d_in[7];
  const float* b_ih1 = (const float*)d_in[8];
  const float* b_hh1 = (const float*)d_in[9];
  const float* fc_w = (const float*)d_in[10];
  const float* fc_b = (const float*)d_in[11];
  float* out = (float*)d_out;

  char* ws = (char*)d_ws;
  size_t off = 0;
  auto carve = [&](size_t bytes) -> char* {
    char* p = ws + off;
    off += (bytes + 255) & ~(size_t)255;
    return p;
  };
  f16* w0i = (f16*)carve((size_t)G4_ * EMB_ * 2);
  f16* w0h = (f16*)carve((size_t)G4_ * HID_ * 2);
  f16* w1i = (f16*)carve((size_t)G4_ * HID_ * 2);
  f16* w1h = (f16*)carve((size_t)G4_ * HID_ * 2);
  f16* x0 = (f16*)carve((size_t)T_ * B_ * EMB_ * 2);
  float* b0s = (float*)carve(G4_ * 4);
  float* b1s = (float*)carve(G4_ * 4);
  f16* h0r = (f16*)carve(257ull * BH * 2);  // slot t+1 = h[t]; slot 0 = zeros
  f16* h1r = (f16*)carve(257ull * BH * 2);
  unsigned* flags = (unsigned*)carve(256 * 4);

  hipMemsetAsync(flags, 0, 256 * 4, stream);
  hipMemsetAsync(h0r, 0, (size_t)BH * 2, stream);
  hipMemsetAsync(h1r, 0, (size_t)BH * 2, stream);

  cvt_kernel<<<(G4_ * EMB_ / 4 + 255) / 256, 256, 0, stream>>>(W_ih0, w0i, G4_ * EMB_ / 4);
  cvt_kernel<<<(G4_ * HID_ / 4 + 255) / 256, 256, 0, stream>>>(W_hh0, w0h, G4_ * HID_ / 4);
  cvt_kernel<<<(G4_ * HID_ / 4 + 255) / 256, 256, 0, stream>>>(W_ih1, w1i, G4_ * HID_ / 4);
  cvt_kernel<<<(G4_ * HID_ / 4 + 255) / 256, 256, 0, stream>>>(W_hh1, w1h, G4_ * HID_ / 4);
  bsum_kernel<<<(G4_ + 255) / 256, 256, 0, stream>>>(b_ih0, b_hh0, b0s, b_ih1, b_hh1, b1s);
  gather_kernel<<<T_ * B_, 128, 0, stream>>>(tokens, emb, x0);

  persist_kernel<<<256, 512, 0, stream>>>(x0, w0i, w0h, w1i, w1h, b0s, b1s,
                                          h0r, h1r, flags);

  fc_kernel<<<NCLS_ / 64, 256, 0, stream>>>(h1r + 256ull * BH, fc_w, fc_b, out);
}

// Round 7
// 2893.380 us; speedup vs baseline: 2.8365x; 1.2161x over previous
//
#include <hip/hip_runtime.h>
#include <hip/hip_bf16.h>

#define B_ 64
#define T_ 256
#define EMB_ 512
#define HID_ 1024
#define G4_ 4096
#define NCLS_ 32000
#define BH (B_ * HID_)

typedef _Float16 f16;
typedef _Float16 f16x8 __attribute__((ext_vector_type(8)));
typedef _Float16 f16x4 __attribute__((ext_vector_type(4)));
typedef _Float16 f16x2 __attribute__((ext_vector_type(2)));
typedef float f32x4 __attribute__((ext_vector_type(4)));
typedef unsigned long long u64;

__device__ __forceinline__ float sigm(float x) { return 1.f / (1.f + __expf(-x)); }

// LLC-coherent (cross-XCD) accessors (R3/R5/R6-proven: relaxed agent-scope atomics).
__device__ __forceinline__ void stg_u32(unsigned* p, unsigned v) {
  __hip_atomic_store(p, v, __ATOMIC_RELAXED, __HIP_MEMORY_SCOPE_AGENT);
}
__device__ __forceinline__ unsigned ldg_u32(const unsigned* p) {
  return __hip_atomic_load(p, __ATOMIC_RELAXED, __HIP_MEMORY_SCOPE_AGENT);
}
__device__ __forceinline__ u64 ldg_u64(const void* p) {
  return __hip_atomic_load((const u64*)p, __ATOMIC_RELAXED, __HIP_MEMORY_SCOPE_AGENT);
}

// ---------------- prep kernels ----------------

__global__ __launch_bounds__(256) void cvt_kernel(const float* __restrict__ src,
                                                  f16* __restrict__ dst, int n4) {
  int i = blockIdx.x * 256 + threadIdx.x;
  if (i < n4) {
    float4 v = ((const float4*)src)[i];
    f16x4 o = {(f16)v.x, (f16)v.y, (f16)v.z, (f16)v.w};
    *(f16x4*)(dst + (size_t)i * 4) = o;
  }
}

__global__ __launch_bounds__(256) void bsum_kernel(const float* __restrict__ a0,
                                                   const float* __restrict__ b0,
                                                   float* __restrict__ o0,
                                                   const float* __restrict__ a1,
                                                   const float* __restrict__ b1,
                                                   float* __restrict__ o1) {
  int i = blockIdx.x * 256 + threadIdx.x;
  if (i < G4_) {
    o0[i] = a0[i] + b0[i];
    o1[i] = a1[i] + b1[i];
  }
}

// x0 layout: [T][B][EMB] fp16
__global__ __launch_bounds__(128) void gather_kernel(const int* __restrict__ tokens,
                                                     const float* __restrict__ emb,
                                                     f16* __restrict__ x0) {
  int blk = blockIdx.x;  // t*64 + b
  int t = blk >> 6, b = blk & 63;
  int tok = tokens[b * T_ + t];
  float4 v = ((const float4*)(emb + (size_t)tok * EMB_))[threadIdx.x];
  f16x4 o = {(f16)v.x, (f16)v.y, (f16)v.z, (f16)v.w};
  *(f16x4*)(x0 + (size_t)blk * EMB_ + threadIdx.x * 4) = o;
}

// ---------------- fused persistent recurrence kernel ----------------
// Identical datapath to R6 (passing, absmax 4.88e-4). ONE change: the grid
// barrier is now two-level -- 256 arrival flags read ONLY by block 0 (sole
// scanner), which then broadcasts a single epoch word (separate 128B sector)
// that all other blocks poll (1 address, s_sleep backoff). Removes the
// 256-wave x 128-address LLC poll storm that queued arrival stores.
__global__ __launch_bounds__(512, 2) void persist_kernel(
    const f16* __restrict__ x0, const f16* __restrict__ w0i,
    const f16* __restrict__ w0h, const f16* __restrict__ w1i,
    const f16* __restrict__ w1h, const float* __restrict__ b0s,
    const float* __restrict__ b1s, f16* __restrict__ h0r,
    f16* __restrict__ h1r, unsigned* flags) {
  __shared__ f16 Ws[32 * 2056];       // 131584 B: 32 rows x (Kcat + 8 pad)
  __shared__ float red[6 * 64 * 17];  // 26112 B: K-partials; reused as pre[32][68]
  __shared__ float cst[512];          // 2 KB cell state [b][u]

  const int layer = blockIdx.x >> 7;
  const int slice = blockIdx.x & 127;
  const int tid = threadIdx.x;
  const int lane = tid & 63, wave = tid >> 6;
  const int mi = wave >> 2, kq = wave & 3;
  const int lr = lane & 15, lk = lane >> 4;
  const int j0 = slice * 8;

  const f16* whh = layer ? w1h : w0h;
  const f16* wih = layer ? w1i : w0i;
  const float* bs = layer ? b1s : b0s;
  f16* hown = layer ? h1r : h0r;
  const int KI = layer ? HID_ : EMB_;
  const int nch = (HID_ + KI) >> 3;   // uint4 chunks per row: 256 / 192
  const int wstr = HID_ + KI + 8;     // 2056 / 1544
  const int nks = (HID_ + KI) >> 5;   // total k-steps: 64 / 48
  const int KQ = nks >> 2;            // per-wave k-steps: 16 / 12

  // ---- one-time: stage Wcat = [W_hh | W_ih] rows into LDS ----
  for (int r = wave * 4; r < wave * 4 + 4; ++r) {
    int grow = (r >> 3) * HID_ + j0 + (r & 7);  // gate*HID + unit
    for (int c = lane; c < nch; c += 64) {
      int kk = c * 8;
      const f16* src = (kk < HID_) ? (whh + (size_t)grow * HID_ + kk)
                                   : (wih + (size_t)grow * KI + (kk - HID_));
      *(uint4*)(Ws + r * wstr + kk) = *(const uint4*)src;
    }
  }
  float brg[4][2];
  {
    int u2 = tid & 3;
#pragma unroll
    for (int g = 0; g < 4; ++g)
#pragma unroll
      for (int e = 0; e < 2; ++e) brg[g][e] = bs[g * HID_ + j0 + u2 * 2 + e];
  }
  for (int i = tid; i < 512; i += 512) cst[i] = 0.f;
  __syncthreads();

  for (int s = 0; s <= T_; ++s) {
    const int t = layer ? s - 1 : s;
    const bool active = layer ? (s >= 1) : (s < T_);

    if (active) {
      f32x4 acc00 = {}, acc01 = {}, acc10 = {}, acc11 = {};
      {
        const int lo = kq * KQ, hi = lo + KQ;
        const int h_hi = hi < 32 ? hi : 32;
        const int x_lo = lo > 32 ? lo : 32;
        const f16* hb = hown + (size_t)t * BH;
        const f16* xb = layer ? (h0r + (size_t)(t + 1) * BH)
                              : (x0 + (size_t)t * (B_ * EMB_));
        const int xstr = layer ? HID_ : EMB_;
        const int r0 = mi * 32 + lr, r1 = r0 + 16;
        const f16* wr0 = Ws + lr * wstr + lk * 8;
        const f16* wr1 = wr0 + 16 * wstr;
#pragma unroll 4
        for (int gk = lo; gk < h_hi; ++gk) {
          f16x8 a0 = *(const f16x8*)(hb + (size_t)r0 * HID_ + gk * 32 + lk * 8);
          f16x8 a1 = *(const f16x8*)(hb + (size_t)r1 * HID_ + gk * 32 + lk * 8);
          f16x8 b0 = *(const f16x8*)(wr0 + gk * 32);
          f16x8 b1 = *(const f16x8*)(wr1 + gk * 32);
          acc00 = __builtin_amdgcn_mfma_f32_16x16x32_f16(a0, b0, acc00, 0, 0, 0);
          acc01 = __builtin_amdgcn_mfma_f32_16x16x32_f16(a0, b1, acc01, 0, 0, 0);
          acc10 = __builtin_amdgcn_mfma_f32_16x16x32_f16(a1, b0, acc10, 0, 0, 0);
          acc11 = __builtin_amdgcn_mfma_f32_16x16x32_f16(a1, b1, acc11, 0, 0, 0);
        }
#pragma unroll 4
        for (int gk = x_lo; gk < hi; ++gk) {
          f16x8 a0 = *(const f16x8*)(xb + (size_t)r0 * xstr + (gk - 32) * 32 + lk * 8);
          f16x8 a1 = *(const f16x8*)(xb + (size_t)r1 * xstr + (gk - 32) * 32 + lk * 8);
          f16x8 b0 = *(const f16x8*)(wr0 + gk * 32);
          f16x8 b1 = *(const f16x8*)(wr1 + gk * 32);
          acc00 = __builtin_amdgcn_mfma_f32_16x16x32_f16(a0, b0, acc00, 0, 0, 0);
          acc01 = __builtin_amdgcn_mfma_f32_16x16x32_f16(a0, b1, acc01, 0, 0, 0);
          acc10 = __builtin_amdgcn_mfma_f32_16x16x32_f16(a1, b0, acc10, 0, 0, 0);
          acc11 = __builtin_amdgcn_mfma_f32_16x16x32_f16(a1, b1, acc11, 0, 0, 0);
        }
      }

      // ---- K-reduce: kq 1..3 publish (17-f32 lane stride: conflict-free) ----
      if (kq) {
        float* rp = red + ((mi * 3 + kq - 1) * 64 + lane) * 17;
        *(f32x4*)(rp) = acc00;      *(f32x4*)(rp + 4) = acc01;
        *(f32x4*)(rp + 8) = acc10;  *(f32x4*)(rp + 12) = acc11;
      }
      __syncthreads();  // A: partials visible
      if (!kq) {
#pragma unroll
        for (int q = 0; q < 3; ++q) {
          const float* rp = red + ((mi * 3 + q) * 64 + lane) * 17;
          acc00 += *(const f32x4*)(rp);      acc01 += *(const f32x4*)(rp + 4);
          acc10 += *(const f32x4*)(rp + 8);  acc11 += *(const f32x4*)(rp + 12);
        }
      }
      __syncthreads();  // B: all red reads done before pre overwrites red
      if (!kq) {
        float* pre = red;  // union
        int col = mi * 32 + lk * 4;
        *(f32x4*)(pre + (0 + lr) * 68 + col) = acc00;        // mf0 nf0
        *(f32x4*)(pre + (16 + lr) * 68 + col) = acc01;       // mf0 nf1
        *(f32x4*)(pre + (0 + lr) * 68 + col + 16) = acc10;   // mf1 nf0
        *(f32x4*)(pre + (16 + lr) * 68 + col + 16) = acc11;  // mf1 nf1
      }
      __syncthreads();  // C: pre ready

      // ---- LSTM elementwise: 256 threads x (1 batch, 2 units) ----
      if (tid < 256) {
        const float* pre = red;
        f16* hout = hown + (size_t)(t + 1) * BH;
        int u2 = tid & 3, b = tid >> 2;
        f16x2 hv;
#pragma unroll
        for (int e = 0; e < 2; ++e) {
          int r = u2 * 2 + e;
          float pi = pre[(0 * 8 + r) * 68 + b] + brg[0][e];
          float pf = pre[(1 * 8 + r) * 68 + b] + brg[1][e];
          float pg = pre[(2 * 8 + r) * 68 + b] + brg[2][e];
          float po = pre[(3 * 8 + r) * 68 + b] + brg[3][e];
          float ig = sigm(pi), fg = sigm(pf), gg = tanhf(pg), og = sigm(po);
          float cn = fg * cst[b * 8 + r] + ig * gg;
          cst[b * 8 + r] = cn;
          hv[e] = (f16)(og * tanhf(cn));
        }
        stg_u32((unsigned*)(hout + (size_t)b * HID_ + j0 + u2 * 2),
                __builtin_bit_cast(unsigned, hv));
      }
    }

    // ---- two-level grid barrier: arrivals -> block0 aggregates -> epoch ----
    if (s < T_) {
      asm volatile("s_waitcnt vmcnt(0)" ::: "memory");
      __syncthreads();  // D: all waves' stores drained
      const unsigned tgt = (unsigned)(s + 1);
      if (tid == 0) stg_u32(&flags[blockIdx.x], tgt);
      if (blockIdx.x == 0) {
        if (wave == 0) {
          const u64* fp = (const u64*)flags;  // 256 arrivals = 128 u64
          int iters = 0;
          for (;;) {
            u64 a = ldg_u64(&fp[lane]);
            u64 b = ldg_u64(&fp[64 + lane]);
            bool ok = ((unsigned)a >= tgt) && ((unsigned)(a >> 32) >= tgt) &&
                      ((unsigned)b >= tgt) && ((unsigned)(b >> 32) >= tgt);
            if (__all(ok)) break;
            if (++iters > 4000000) break;  // safety valve: degrade, don't hang
            __builtin_amdgcn_s_sleep(1);
          }
          if (lane == 0) stg_u32(&flags[384], tgt);  // epoch (own 128B sector)
        }
      } else {
        if (wave == 0) {
          int iters = 0;
          while (ldg_u32(&flags[384]) < tgt) {
            if (++iters > 4000000) break;  // safety valve
            __builtin_amdgcn_s_sleep(3);
          }
        }
      }
      __syncthreads();  // E: release whole block
    }
  }
}

// ---------------- FC kernel: out = h1_last @ fc_w^T + fc_b ----------------
__global__ __launch_bounds__(256) void fc_kernel(const f16* __restrict__ A,
                                                 const float* __restrict__ fcw,
                                                 const float* __restrict__ fcb,
                                                 float* __restrict__ out) {
  const int n0 = blockIdx.x * 64;
  __shared__ char smem[18432];
  f16* As = (f16*)smem;
  f16* Bs = (f16*)(smem + 9216);
  const int tid = threadIdx.x;
  const int lane = tid & 63, wave = tid >> 6;
  const int wm = wave & 1, wn = wave >> 1;
  const int lr = lane & 15, lk = lane >> 4;
  f32x4 acc[2][2] = {};

  for (int kt = 0; kt < HID_ / 64; ++kt) {
    const int k0 = kt * 64;
    __syncthreads();
#pragma unroll
    for (int i = 0; i < 2; ++i) {
      int id = tid + 256 * i;
      int r = id >> 3, c8 = id & 7;
      uint4 av = *(const uint4*)(A + (size_t)r * HID_ + k0 + c8 * 8);
      *(uint4*)(As + r * 72 + c8 * 8) = av;
    }
#pragma unroll
    for (int i = 0; i < 4; ++i) {
      int id = tid + 256 * i;
      int r = id >> 4, c4 = id & 15;
      float4 v = *(const float4*)(fcw + (size_t)(n0 + r) * HID_ + k0 + c4 * 4);
      f16x4 o = {(f16)v.x, (f16)v.y, (f16)v.z, (f16)v.w};
      *(f16x4*)(Bs + r * 72 + c4 * 4) = o;
    }
    __syncthreads();
#pragma unroll
    for (int ks = 0; ks < 2; ++ks) {
      f16x8 a0 = *(const f16x8*)(As + (wm * 32 + lr) * 72 + ks * 32 + lk * 8);
      f16x8 a1 = *(const f16x8*)(As + (wm * 32 + 16 + lr) * 72 + ks * 32 + lk * 8);
      f16x8 b0 = *(const f16x8*)(Bs + (wn * 32 + lr) * 72 + ks * 32 + lk * 8);
      f16x8 b1 = *(const f16x8*)(Bs + (wn * 32 + 16 + lr) * 72 + ks * 32 + lk * 8);
      acc[0][0] = __builtin_amdgcn_mfma_f32_16x16x32_f16(a0, b0, acc[0][0], 0, 0, 0);
      acc[0][1] = __builtin_amdgcn_mfma_f32_16x16x32_f16(a0, b1, acc[0][1], 0, 0, 0);
      acc[1][0] = __builtin_amdgcn_mfma_f32_16x16x32_f16(a1, b0, acc[1][0], 0, 0, 0);
      acc[1][1] = __builtin_amdgcn_mfma_f32_16x16x32_f16(a1, b1, acc[1][1], 0, 0, 0);
    }
  }

#pragma unroll
  for (int mf = 0; mf < 2; ++mf)
#pragma unroll
    for (int nf = 0; nf < 2; ++nf) {
      int n = n0 + wn * 32 + nf * 16 + lr;
      float bias = fcb[n];
      int bbase = wm * 32 + mf * 16 + lk * 4;
#pragma unroll
      for (int rg = 0; rg < 4; ++rg)
        out[(size_t)(bbase + rg) * NCLS_ + n] = acc[mf][nf][rg] + bias;
    }
}

// ---------------- launch ----------------

extern "C" void kernel_launch(void* const* d_in, const int* in_sizes, int n_in,
                              void* d_out, int out_size, void* d_ws,
                              size_t ws_size, hipStream_t stream) {
  const int* tokens = (const int*)d_in[0];
  const float* emb = (const float*)d_in[1];
  const float* W_ih0 = (const float*)d_in[2];
  const float* W_hh0 = (const float*)d_in[3];
  const float* b_ih0 = (const float*)d_in[4];
  const float* b_hh0 = (const float*)d_in[5];
  const float* W_ih1 = (const float*)d_in[6];
  const float* W_hh1 = (const float*)d_in[7];
  const float* b_ih1 = (const float*)d_in[8];
  const float* b_hh1 = (const float*)d_in[9];
  const float* fc_w = (const float*)d_in[10];
  const float* fc_b = (const float*)d_in[11];
  float* out = (float*)d_out;

  char* ws = (char*)d_ws;
  size_t off = 0;
  auto carve = [&](size_t bytes) -> char* {
    char* p = ws + off;
    off += (bytes + 255) & ~(size_t)255;
    return p;
  };
  f16* w0i = (f16*)carve((size_t)G4_ * EMB_ * 2);
  f16* w0h = (f16*)carve((size_t)G4_ * HID_ * 2);
  f16* w1i = (f16*)carve((size_t)G4_ * HID_ * 2);
  f16* w1h = (f16*)carve((size_t)G4_ * HID_ * 2);
  f16* x0 = (f16*)carve((size_t)T_ * B_ * EMB_ * 2);
  float* b0s = (float*)carve(G4_ * 4);
  float* b1s = (float*)carve(G4_ * 4);
  f16* h0r = (f16*)carve(257ull * BH * 2);  // slot t+1 = h[t]; slot 0 = zeros
  f16* h1r = (f16*)carve(257ull * BH * 2);
  unsigned* flags = (unsigned*)carve(512 * 4);  // [0..255] arrivals, [384] epoch

  hipMemsetAsync(flags, 0, 512 * 4, stream);
  hipMemsetAsync(h0r, 0, (size_t)BH * 2, stream);
  hipMemsetAsync(h1r, 0, (size_t)BH * 2, stream);

  cvt_kernel<<<(G4_ * EMB_ / 4 + 255) / 256, 256, 0, stream>>>(W_ih0, w0i, G4_ * EMB_ / 4);
  cvt_kernel<<<(G4_ * HID_ / 4 + 255) / 256, 256, 0, stream>>>(W_hh0, w0h, G4_ * HID_ / 4);
  cvt_kernel<<<(G4_ * HID_ / 4 + 255) / 256, 256, 0, stream>>>(W_ih1, w1i, G4_ * HID_ / 4);
  cvt_kernel<<<(G4_ * HID_ / 4 + 255) / 256, 256, 0, stream>>>(W_hh1, w1h, G4_ * HID_ / 4);
  bsum_kernel<<<(G4_ + 255) / 256, 256, 0, stream>>>(b_ih0, b_hh0, b0s, b_ih1, b_hh1, b1s);
  gather_kernel<<<T_ * B_, 128, 0, stream>>>(tokens, emb, x0);

  persist_kernel<<<256, 512, 0, stream>>>(x0, w0i, w0h, w1i, w1h, b0s, b1s,
                                          h0r, h1r, flags);

  fc_kernel<<<NCLS_ / 64, 256, 0, stream>>>(h1r + 256ull * BH, fc_w, fc_b, out);
}